// Round 8
// baseline (406.365 us; speedup 1.0000x reference)
//
#include <hip/hip_runtime.h>
#include <math.h>

#define N   8192
#define D   512
#define C   16
#define HM  256
#define HG  64
#define KMAX 128   // max neighbors per row (mean ~65, 12-sigma safe)
#define INF 0x7FFFFFFF
#define NREP 32    // H accumulator replicas (chain 2048 -> 64)
#define LREP 64    // loss accumulator replicas

typedef __attribute__((ext_vector_type(8))) short bf16x8;
typedef __attribute__((ext_vector_type(4))) float f32x4;
typedef unsigned long long ull;

__device__ __forceinline__ unsigned short f2b(float x) {
  union { float f; unsigned int u; } v; v.f = x;
  unsigned int r = v.u + 0x7FFFu + ((v.u >> 16) & 1u);  // RNE
  return (unsigned short)(r >> 16);
}

// header layout (u64 units): Hrep[32][272] | lossrep[64] | done(2 ints in 1 u64)
#define HDR_U64 8832   // 8704 + 64 + 1, rounded to 16B multiple

// ---------------- K0: prep: feature->bf16, Wcat->bf16 T, Wm2->bf16 T, zero counters ------------
__global__ __launch_bounds__(256) void prep_kernel(const float* __restrict__ feat,
    const float* __restrict__ Wm1, const float* __restrict__ W1,
    const float* __restrict__ Wm2, unsigned short* __restrict__ Abf,
    unsigned short* __restrict__ Wt, unsigned short* __restrict__ Wm2tb,
    int* __restrict__ rowcnt, ull* __restrict__ header) {
  const int tid = blockIdx.x * 256 + threadIdx.x;  // 524288 threads
  const float4 a = *(const float4*)&feat[(size_t)tid * 8];
  const float4 b = *(const float4*)&feat[(size_t)tid * 8 + 4];
  ushort4 lo, hi;
  lo.x = f2b(a.x); lo.y = f2b(a.y); lo.z = f2b(a.z); lo.w = f2b(a.w);
  hi.x = f2b(b.x); hi.y = f2b(b.y); hi.z = f2b(b.z); hi.w = f2b(b.w);
  *(ushort4*)&Abf[(size_t)tid * 8] = lo;
  *(ushort4*)&Abf[(size_t)tid * 8 + 4] = hi;
  if (tid < 320 * 512) {  // Wt[n][k]
    const int n = tid >> 9, k = tid & 511;
    const float v = (n < 256) ? Wm1[k * 256 + n] : W1[k * 64 + (n - 256)];
    Wt[tid] = f2b(v);
  }
  if (tid < 16 * 256) {   // Wm2tb[c][k] = Wm2[k][c]
    const int cc = tid >> 8, k = tid & 255;
    Wm2tb[tid] = f2b(Wm2[k * 16 + cc]);
  }
  if (tid < N) rowcnt[tid] = 0;
  if (tid < HDR_U64) header[tid] = 0ull;
}

// ---------------- K1: adj upper-triangle scan, 4 balanced rows/block, interleaved loads --------
__global__ __launch_bounds__(256) void adj_tri(const float* __restrict__ adj,
    int* __restrict__ rowcnt, int* __restrict__ colidx) {
  const int t = threadIdx.x, b = blockIdx.x;  // b in [0,2048)
  int rows[4];
  rows[0] = 2 * b; rows[1] = 2 * b + 1;
  rows[2] = N - 2 - 2 * b; rows[3] = N - 1 - 2 * b;
  const float4* base[4];
  int c0[4], nch[4];
  int maxn = 0;
  #pragma unroll
  for (int r = 0; r < 4; ++r) {
    c0[r] = rows[r] & ~3;
    nch[r] = (N - c0[r]) >> 2;
    base[r] = (const float4*)(adj + (size_t)rows[r] * N + c0[r]);
    maxn = max(maxn, nch[r]);
  }
  for (int p = t; p < maxn; p += 256) {
    float4 v[4];
    bool act[4];
    #pragma unroll
    for (int r = 0; r < 4; ++r) {
      act[r] = p < nch[r];
      if (act[r]) v[r] = base[r][p];    // independent loads in flight
    }
    #pragma unroll
    for (int r = 0; r < 4; ++r) {
      if (!act[r]) continue;
      const float4 vv = v[r];
      if (vv.x + vv.y + vv.z + vv.w > 0.f) {   // adj is 0/1: skip all-zero chunks
        const int row = rows[r];
        const int j = c0[r] + p * 4;
        const float e[4] = {vv.x, vv.y, vv.z, vv.w};
        #pragma unroll
        for (int q = 0; q < 4; ++q) {
          const int jj = j + q;
          if (e[q] > 0.f && jj >= row) {
            int pos = atomicAdd(&rowcnt[row], 1);
            if (pos < KMAX) colidx[row * KMAX + pos] = jj;
            if (jj > row) {
              pos = atomicAdd(&rowcnt[jj], 1);
              if (pos < KMAX) colidx[(size_t)jj * KMAX + pos] = row;
            }
          }
        }
      }
    }
  }
}

// ---------------- K2: GEMM (BM=32, 256 blocks) + MLP layer2 + softmax --------------------------
__global__ __launch_bounds__(256) void gemm_mlp(
    const bf16x8* __restrict__ Abf, const bf16x8* __restrict__ Wt,
    const float* __restrict__ bm1, const bf16x8* __restrict__ Wm2tb,
    const float* __restrict__ bm2, const float* __restrict__ labels1h,
    const int* __restrict__ mask, float* __restrict__ Bmat,
    float* __restrict__ softy, float* __restrict__ X1) {
  __shared__ unsigned short c1[32][264];   // bf16 C1 tile (row stride 528B)
  const int l = threadIdx.x & 63, w = threadIdx.x >> 6;
  const int m0 = blockIdx.x * 32;
  const int kb = l >> 4, cl = l & 15;
  const int rw = (w >> 1) * 16;          // row half: 0 or 16
  const int nt0 = (w & 1) * 10;          // tile half: 0..9 or 10..19
  const int row = m0 + rw + cl;
  const bf16x8* arow = Abf + (size_t)row * 64 + kb;
  f32x4 acc[10] = {};
  for (int kk = 0; kk < 16; ++kk) {
    const bf16x8 af = arow[kk * 4];
    #pragma unroll
    for (int i = 0; i < 10; ++i) {
      const bf16x8 bfr = Wt[(size_t)((nt0 + i) * 16 + cl) * 64 + kk * 4 + kb];
      acc[i] = __builtin_amdgcn_mfma_f32_16x16x32_bf16(af, bfr, acc[i], 0, 0, 0);
    }
  }
  // epilogue: C/D layout col=l&15, row=(l>>4)*4+r
  const int rl0 = rw + kb * 4;
  #pragma unroll
  for (int i = 0; i < 10; ++i) {
    const int nt = nt0 + i;
    const int col = nt * 16 + cl;
    if (nt < 16) {
      const float bv = bm1[col];
      #pragma unroll
      for (int r = 0; r < 4; ++r)
        c1[rl0 + r][col] = f2b(fmaxf(acc[i][r] + bv, 0.f));
    } else {
      const int xc = col - 256;
      #pragma unroll
      for (int r = 0; r < 4; ++r)
        X1[(size_t)(m0 + rl0 + r) * HG + xc] = acc[i][r];
    }
  }
  __syncthreads();
  // layer 2 (waves 0,2): B = softmax(C1 @ Wm2 + bm2) for rows m0+rw..+15
  if ((w & 1) == 0) {
    f32x4 acc2 = {0.f, 0.f, 0.f, 0.f};
    #pragma unroll
    for (int kk = 0; kk < 8; ++kk) {
      const bf16x8 a2 = *(const bf16x8*)&c1[rw + cl][kk * 32 + kb * 8];
      const bf16x8 b2v = Wm2tb[(size_t)cl * 32 + kk * 4 + kb];
      acc2 = __builtin_amdgcn_mfma_f32_16x16x32_bf16(a2, b2v, acc2, 0, 0, 0);
    }
    const float bm2v = bm2[cl];
    #pragma unroll
    for (int r = 0; r < 4; ++r) {
      float v = acc2[r] + bm2v;
      float m = v;
      #pragma unroll
      for (int s = 1; s < 16; s <<= 1) m = fmaxf(m, __shfl_xor(m, s));
      const float e = __expf(v - m);
      float ssum = e;
      #pragma unroll
      for (int s = 1; s < 16; s <<= 1) ssum += __shfl_xor(ssum, s);
      const float bb = e / ssum;
      const int grow = m0 + rw + kb * 4 + r;
      Bmat[grow * C + cl] = bb;
      softy[grow * C + cl] = mask[grow] ? labels1h[grow * C + cl] : bb;
    }
  }
}

// ---------------- K3: sort + nbrsum + REPLICATED fixed-point H atomics; ticket finalizes -------
__global__ __launch_bounds__(256) void sort_h(int* __restrict__ rowcnt,
    int* __restrict__ colidx, const float* __restrict__ softy,
    ull* __restrict__ Hrep, int* __restrict__ done,
    const float* __restrict__ bias, float* __restrict__ H_o,
    float* __restrict__ Q_o, float* __restrict__ Qws) {
  __shared__ int cs[4][128];
  __shared__ float nb[4][16], sy[4][16];
  __shared__ float Hs[256], Qs[256], rs[16], dd[16];
  __shared__ int tk;
  const int t = threadIdx.x, lane = t & 63, w = t >> 6;
  const int row = blockIdx.x * 4 + w;
  // ---- deterministic bitonic sort of the atomically-appended neighbor list ----
  const int cnt = min(rowcnt[row], KMAX);
  if (lane == 0) rowcnt[row] = cnt;
  int e0 = (lane < cnt) ? colidx[row * KMAX + lane] : INF;
  int e1 = (lane + 64 < cnt) ? colidx[row * KMAX + lane + 64] : INF;
  #pragma unroll
  for (int k = 2; k <= 128; k <<= 1) {
    if (k == 128) { const int mn = min(e0, e1), mx = max(e0, e1); e0 = mn; e1 = mx; }
    #pragma unroll
    for (int j = (k == 128) ? 32 : (k >> 1); j > 0; j >>= 1) {
      const bool up = (lane & k) == 0;
      const bool upHi = ((lane + 64) & k) == 0;
      const bool lower = (lane & j) == 0;
      const int o0 = __shfl_xor(e0, j);
      const int o1 = __shfl_xor(e1, j);
      const int mn0 = min(e0, o0), mx0 = max(e0, o0);
      const int mn1 = min(e1, o1), mx1 = max(e1, o1);
      e0 = (up == lower) ? mn0 : mx0;
      e1 = (upHi == lower) ? mn1 : mx1;
    }
  }
  if (lane < cnt) colidx[row * KMAX + lane] = e0;
  if (lane + 64 < cnt) colidx[row * KMAX + lane + 64] = e1;
  cs[w][lane] = e0;
  cs[w][lane + 64] = e1;
  if (t < 64) sy[t >> 4][t & 15] = softy[(blockIdx.x * 4 + (t >> 4)) * C + (t & 15)];
  __syncthreads();
  // ---- nbrsum for this wave's row ----
  {
    const int c = lane & 15, grp = lane >> 4;
    float acc = 0.f;
    for (int e = grp; e < cnt; e += 4)
      acc += softy[cs[w][e] * C + c];
    acc += __shfl_xor(acc, 16);
    acc += __shfl_xor(acc, 32);
    if (lane < 16) nb[w][c] = acc;
  }
  __syncthreads();
  // ---- fixed-point H partials into replica (blockIdx & 31): chain length 64 ----
  {
    ull* rep = Hrep + (size_t)(blockIdx.x & (NREP - 1)) * 272;
    const int c = t >> 4, cp = t & 15;
    ull hterm = 0;
    #pragma unroll
    for (int r = 0; r < 4; ++r)
      hterm += (ull)((double)nb[r][c] * (double)sy[r][cp] * 4294967296.0 + 0.5);
    atomicAdd(&rep[t], hterm);
    if (cp == 0) {
      ull dterm = 0;
      #pragma unroll
      for (int r = 0; r < 4; ++r)
        dterm += (ull)((double)nb[r][c] * 4294967296.0 + 0.5);
      atomicAdd(&rep[256 + c], dterm);
    }
  }
  __threadfence();
  __syncthreads();
  if (t == 0) tk = atomicAdd(done, 1);
  __syncthreads();
  if (tk != 2047) return;
  // ---- last block: sum replicas, finalize H, Q ----
  const int c = t >> 4, cp = t & 15;
  ull hv = 0;
  #pragma unroll
  for (int r = 0; r < NREP; ++r) hv += atomicAdd(&Hrep[(size_t)r * 272 + t], 0ull);
  if (t < 16) {
    ull dv = 0;
    #pragma unroll
    for (int r = 0; r < NREP; ++r) dv += atomicAdd(&Hrep[(size_t)r * 272 + 256 + t], 0ull);
    dd[t] = (float)((double)dv / 4294967296.0);
  }
  __syncthreads();
  const float Hv = (float)((double)hv / 4294967296.0) / dd[c];
  Hs[t] = Hv;
  H_o[t] = Hv;
  __syncthreads();
  float q = 0.f;
  for (int k = 0; k < 16; ++k) q = fmaf(Hs[c * 16 + k], Hs[cp * 16 + k], q);
  q *= bias[t];
  Qs[t] = q;
  __syncthreads();
  if (t < 16) {
    float s = 0.f;
    for (int k = 0; k < 16; ++k) s += Qs[t * 16 + k];
    rs[t] = s;
  }
  __syncthreads();
  const float Qv = q / rs[c];
  Q_o[t] = Qv;
  Qws[t] = Qv;
}

// ---------------- K4: fused edge softmax + GCN layer1 + X2 head (unchanged, verified) ----------
__global__ __launch_bounds__(256) void edge_gcn1(const float* __restrict__ Bmat,
    const float* __restrict__ Q, const int* __restrict__ rowcnt,
    const int* __restrict__ colidx, const float* __restrict__ X1,
    const float* __restrict__ b1, const float* __restrict__ W2,
    float* __restrict__ gval, float* __restrict__ X2) {
  __shared__ float Prow[4][16];
  __shared__ float gv[4][128];
  __shared__ int cs[4][128];
  const int lane = threadIdx.x & 63, w = threadIdx.x >> 6;
  const int row = blockIdx.x * 4 + w;
  const int c = lane & 15, grp = lane >> 4;
  float acc = 0.f;
  for (int k = grp * 4; k < grp * 4 + 4; ++k)
    acc = fmaf(Bmat[row * C + k], Q[k * C + c], acc);
  acc += __shfl_xor(acc, 16);
  acc += __shfl_xor(acc, 32);
  if (lane < 16) Prow[w][c] = acc;
  __syncthreads();
  const int cnt = rowcnt[row];
  const int col0 = (lane < cnt) ? colidx[row * KMAX + lane] : 0;
  const int col1 = (lane + 64 < cnt) ? colidx[row * KMAX + lane + 64] : 0;
  float s0 = -1e30f, s1 = -1e30f;
  if (lane < cnt) {
    float s = 0.f;
    for (int k = 0; k < 16; ++k) s = fmaf(Prow[w][k], Bmat[col0 * C + k], s);
    s0 = s;
  }
  if (lane + 64 < cnt) {
    float s = 0.f;
    for (int k = 0; k < 16; ++k) s = fmaf(Prow[w][k], Bmat[col1 * C + k], s);
    s1 = s;
  }
  float m = fmaxf(s0, s1);
  for (int s = 1; s < 64; s <<= 1) m = fmaxf(m, __shfl_xor(m, s));
  const float e0 = __expf(s0 - m), e1 = __expf(s1 - m);
  float ssum = e0 + e1;
  for (int s = 1; s < 64; s <<= 1) ssum += __shfl_xor(ssum, s);
  const float inv = 1.f / ssum;
  const float g0 = e0 * inv, g1 = e1 * inv;
  if (lane < cnt) gval[row * KMAX + lane] = g0;
  if (lane + 64 < cnt) gval[row * KMAX + lane + 64] = g1;
  gv[w][lane] = g0; gv[w][lane + 64] = g1;
  cs[w][lane] = col0; cs[w][lane + 64] = col1;
  __syncthreads();
  float hacc = 0.f;
  for (int e = 0; e < cnt; ++e)
    hacc = fmaf(gv[w][e], X1[(size_t)cs[w][e] * HG + lane], hacc);
  const float h = fmaxf(hacc + b1[lane], 0.f);
  float x[16];
  #pragma unroll
  for (int cc = 0; cc < 16; ++cc) x[cc] = h * W2[lane * C + cc];
  #pragma unroll
  for (int s = 1; s < 64; s <<= 1)
    #pragma unroll
    for (int cc = 0; cc < 16; ++cc) x[cc] += __shfl_xor(x[cc], s);
  float v = x[0];
  #pragma unroll
  for (int cc = 1; cc < 16; ++cc) v = (lane == cc) ? x[cc] : v;
  if (lane < 16) X2[row * C + lane] = v;
}

// ---------------- K5: output/logits + replicated fixed-point loss; ticket writes loss ----------
__global__ __launch_bounds__(256) void gcn2_loss(const float* __restrict__ X2,
    const float* __restrict__ b2, const int* __restrict__ rowcnt,
    const int* __restrict__ colidx, const float* __restrict__ gval,
    const float* __restrict__ Bmat, const int* __restrict__ idx,
    const int* __restrict__ label, ull* __restrict__ lossrep,
    int* __restrict__ done2, float* __restrict__ out_logits,
    float* __restrict__ out_output, float* __restrict__ out_loss) {
  __shared__ float lg[4][16];
  __shared__ int tk;
  const int t = threadIdx.x, lane = t & 63, w = t >> 6;
  const int row = blockIdx.x * 4 + w;
  const int c = lane & 15, grp = lane >> 4;
  const int cnt = rowcnt[row];
  float acc = 0.f;
  for (int e = grp; e < cnt; e += 4)
    acc = fmaf(gval[row * KMAX + e], X2[colidx[row * KMAX + e] * C + c], acc);
  acc += __shfl_xor(acc, 16);
  acc += __shfl_xor(acc, 32);
  acc += b2[c];
  float m = acc;
  for (int s = 1; s < 16; s <<= 1) m = fmaxf(m, __shfl_xor(m, s));
  const float e = __expf(acc - m);
  float ssum = e;
  for (int s = 1; s < 16; s <<= 1) ssum += __shfl_xor(ssum, s);
  const float lgv = e / ssum;
  if (lane < 16) {
    out_output[row * C + c] = acc;
    out_logits[row * C + c] = lgv;
    lg[w][c] = lgv;
  }
  __syncthreads();
  // loss contributions for this wave's row -> replica (blockIdx & 63)
  for (int i = lane; i < 1024; i += 64) {
    if (idx[i] == row) {
      const int ll = label[i];
      const float contrib = -(logf(lg[w][ll]) + logf(Bmat[row * C + ll]));
      atomicAdd(&lossrep[blockIdx.x & (LREP - 1)], (ull)((double)contrib * 67108864.0 + 0.5));
    }
  }
  __threadfence();
  __syncthreads();
  if (t == 0) tk = atomicAdd(done2, 1);
  __syncthreads();
  if (tk == 2047) {
    __shared__ float sl[64];
    if (t < LREP) {
      const ull v = atomicAdd(&lossrep[t], 0ull);
      sl[t] = (float)((double)v / 67108864.0);
    }
    __syncthreads();
    if (t == 0) {
      float s = 0.f;
      #pragma unroll
      for (int i = 0; i < LREP; ++i) s += sl[i];
      out_loss[0] = s / 1024.f;
    }
  }
}

extern "C" void kernel_launch(void* const* d_in, const int* in_sizes, int n_in,
                              void* d_out, int out_size, void* d_ws, size_t ws_size,
                              hipStream_t stream) {
  const float* feature  = (const float*)d_in[0];
  const float* adj      = (const float*)d_in[1];
  const float* labels1h = (const float*)d_in[2];
  const float* bias     = (const float*)d_in[3];
  const float* Wm1 = (const float*)d_in[4];
  const float* bm1 = (const float*)d_in[5];
  const float* Wm2 = (const float*)d_in[6];
  const float* bm2 = (const float*)d_in[7];
  const float* W1  = (const float*)d_in[8];
  const float* b1  = (const float*)d_in[9];
  const float* W2  = (const float*)d_in[10];
  const float* b2  = (const float*)d_in[11];
  const int* idx   = (const int*)d_in[12];
  const int* label = (const int*)d_in[13];
  const int* mask  = (const int*)d_in[14];

  float* out = (float*)d_out;
  float* logits_o = out;                 // N*C
  float* loss_o   = out + (size_t)N * C; // 1
  float* H_o      = loss_o + 1;          // 256
  float* Q_o      = H_o + 256;           // 256
  float* outp_o   = Q_o + 256;           // N*C

  ull* header  = (ull*)d_ws;
  ull* Hrep    = header;                  // 32 * 272
  ull* lossrep = header + (size_t)NREP * 272;   // 64
  int* done    = (int*)(lossrep + LREP);  // done[0], done[1]
  float* p = (float*)(header + 8770);     // 16B-aligned past header
  float* X1     = p; p += (size_t)N * HG;
  float* Bmat   = p; p += (size_t)N * C;
  float* softy  = p; p += (size_t)N * C;
  float* X2     = p; p += (size_t)N * C;
  float* Qws    = p; p += 256;
  int* rowcnt = (int*)p; p += N;
  int* colidx = (int*)p; p += (size_t)N * KMAX;
  float* gval = p; p += (size_t)N * KMAX;
  unsigned short* Abf   = (unsigned short*)p;        // N*D bf16
  unsigned short* Wt    = Abf + (size_t)N * D;       // 320*512
  unsigned short* Wm2tb = Wt + 320 * 512;            // 16*256

  prep_kernel<<<(N * D / 8) / 256, 256, 0, stream>>>(feature, Wm1, W1, Wm2, Abf, Wt, Wm2tb, rowcnt, header);
  adj_tri<<<N / 4, 256, 0, stream>>>(adj, rowcnt, colidx);
  gemm_mlp<<<N / 32, 256, 0, stream>>>((const bf16x8*)Abf, (const bf16x8*)Wt, bm1,
      (const bf16x8*)Wm2tb, bm2, labels1h, mask, Bmat, softy, X1);
  sort_h<<<N / 4, 256, 0, stream>>>(rowcnt, colidx, softy, Hrep, done,
      bias, H_o, Q_o, Qws);
  edge_gcn1<<<N / 4, 256, 0, stream>>>(Bmat, Qws, rowcnt, colidx, X1, b1, W2, gval, X2);
  gcn2_loss<<<N / 4, 256, 0, stream>>>(X2, b2, rowcnt, colidx, gval, Bmat, idx, label,
      lossrep, done + 1, logits_o, outp_o, loss_o);
}

// Round 9
// 153.558 us; speedup vs baseline: 2.6463x; 2.6463x over previous
//
#include <hip/hip_runtime.h>
#include <math.h>

#define N   8192
#define D   512
#define C   16
#define HM  256
#define HG  64
#define KMAX 128   // max neighbors per row (mean ~65, 12-sigma safe)
#define INF 0x7FFFFFFF

typedef __attribute__((ext_vector_type(8))) short bf16x8;
typedef __attribute__((ext_vector_type(4))) float f32x4;

__device__ __forceinline__ unsigned short f2b(float x) {
  union { float f; unsigned int u; } v; v.f = x;
  unsigned int r = v.u + 0x7FFFu + ((v.u >> 16) & 1u);  // RNE
  return (unsigned short)(r >> 16);
}

// ---------------- K0: prep: feature->bf16, Wcat->bf16 T, Wm2->bf16 T, rowcnt=0 -----------------
__global__ __launch_bounds__(256) void prep_kernel(const float* __restrict__ feat,
    const float* __restrict__ Wm1, const float* __restrict__ W1,
    const float* __restrict__ Wm2, unsigned short* __restrict__ Abf,
    unsigned short* __restrict__ Wt, unsigned short* __restrict__ Wm2tb,
    int* __restrict__ rowcnt) {
  const int tid = blockIdx.x * 256 + threadIdx.x;  // 524288 threads
  const float4 a = *(const float4*)&feat[(size_t)tid * 8];
  const float4 b = *(const float4*)&feat[(size_t)tid * 8 + 4];
  ushort4 lo, hi;
  lo.x = f2b(a.x); lo.y = f2b(a.y); lo.z = f2b(a.z); lo.w = f2b(a.w);
  hi.x = f2b(b.x); hi.y = f2b(b.y); hi.z = f2b(b.z); hi.w = f2b(b.w);
  *(ushort4*)&Abf[(size_t)tid * 8] = lo;
  *(ushort4*)&Abf[(size_t)tid * 8 + 4] = hi;
  if (tid < 320 * 512) {  // Wt[n][k]
    const int n = tid >> 9, k = tid & 511;
    const float v = (n < 256) ? Wm1[k * 256 + n] : W1[k * 64 + (n - 256)];
    Wt[tid] = f2b(v);
  }
  if (tid < 16 * 256) {   // Wm2tb[c][k] = Wm2[k][c]
    const int cc = tid >> 8, k = tid & 255;
    Wm2tb[tid] = f2b(Wm2[k * 16 + cc]);
  }
  if (tid < N) rowcnt[tid] = 0;
}

// ---------------- K1: adj upper-triangle scan, 4 balanced rows/block, interleaved loads --------
__global__ __launch_bounds__(256) void adj_tri(const float* __restrict__ adj,
    int* __restrict__ rowcnt, int* __restrict__ colidx) {
  const int t = threadIdx.x, b = blockIdx.x;  // b in [0,2048)
  int rows[4];
  rows[0] = 2 * b; rows[1] = 2 * b + 1;
  rows[2] = N - 2 - 2 * b; rows[3] = N - 1 - 2 * b;
  const float4* base[4];
  int c0[4], nch[4];
  int maxn = 0;
  #pragma unroll
  for (int r = 0; r < 4; ++r) {
    c0[r] = rows[r] & ~3;
    nch[r] = (N - c0[r]) >> 2;
    base[r] = (const float4*)(adj + (size_t)rows[r] * N + c0[r]);
    maxn = max(maxn, nch[r]);
  }
  for (int p = t; p < maxn; p += 256) {
    float4 v[4];
    bool act[4];
    #pragma unroll
    for (int r = 0; r < 4; ++r) {
      act[r] = p < nch[r];
      if (act[r]) v[r] = base[r][p];    // independent loads in flight
    }
    #pragma unroll
    for (int r = 0; r < 4; ++r) {
      if (!act[r]) continue;
      const float4 vv = v[r];
      if (vv.x + vv.y + vv.z + vv.w > 0.f) {   // adj is 0/1: skip all-zero chunks
        const int row = rows[r];
        const int j = c0[r] + p * 4;
        const float e[4] = {vv.x, vv.y, vv.z, vv.w};
        #pragma unroll
        for (int q = 0; q < 4; ++q) {
          const int jj = j + q;
          if (e[q] > 0.f && jj >= row) {
            int pos = atomicAdd(&rowcnt[row], 1);
            if (pos < KMAX) colidx[row * KMAX + pos] = jj;
            if (jj > row) {
              pos = atomicAdd(&rowcnt[jj], 1);
              if (pos < KMAX) colidx[(size_t)jj * KMAX + pos] = row;
            }
          }
        }
      }
    }
  }
}

// ---------------- K2: GEMM (BM=32, 256 blocks) + MLP layer2 + softmax --------------------------
__global__ __launch_bounds__(256) void gemm_mlp(
    const bf16x8* __restrict__ Abf, const bf16x8* __restrict__ Wt,
    const float* __restrict__ bm1, const bf16x8* __restrict__ Wm2tb,
    const float* __restrict__ bm2, const float* __restrict__ labels1h,
    const int* __restrict__ mask, float* __restrict__ Bmat,
    float* __restrict__ softy, float* __restrict__ X1) {
  __shared__ unsigned short c1[32][264];   // bf16 C1 tile (row stride 528B)
  const int l = threadIdx.x & 63, w = threadIdx.x >> 6;
  const int m0 = blockIdx.x * 32;
  const int kb = l >> 4, cl = l & 15;
  const int rw = (w >> 1) * 16;          // row half: 0 or 16
  const int nt0 = (w & 1) * 10;          // tile half: 0..9 or 10..19
  const int row = m0 + rw + cl;
  const bf16x8* arow = Abf + (size_t)row * 64 + kb;
  f32x4 acc[10] = {};
  for (int kk = 0; kk < 16; ++kk) {
    const bf16x8 af = arow[kk * 4];
    #pragma unroll
    for (int i = 0; i < 10; ++i) {
      const bf16x8 bfr = Wt[(size_t)((nt0 + i) * 16 + cl) * 64 + kk * 4 + kb];
      acc[i] = __builtin_amdgcn_mfma_f32_16x16x32_bf16(af, bfr, acc[i], 0, 0, 0);
    }
  }
  // epilogue: C/D layout col=l&15, row=(l>>4)*4+r
  const int rl0 = rw + kb * 4;
  #pragma unroll
  for (int i = 0; i < 10; ++i) {
    const int nt = nt0 + i;
    const int col = nt * 16 + cl;
    if (nt < 16) {
      const float bv = bm1[col];
      #pragma unroll
      for (int r = 0; r < 4; ++r)
        c1[rl0 + r][col] = f2b(fmaxf(acc[i][r] + bv, 0.f));
    } else {
      const int xc = col - 256;
      #pragma unroll
      for (int r = 0; r < 4; ++r)
        X1[(size_t)(m0 + rl0 + r) * HG + xc] = acc[i][r];
    }
  }
  __syncthreads();
  // layer 2 (waves 0,2): B = softmax(C1 @ Wm2 + bm2) for rows m0+rw..+15
  if ((w & 1) == 0) {
    f32x4 acc2 = {0.f, 0.f, 0.f, 0.f};
    #pragma unroll
    for (int kk = 0; kk < 8; ++kk) {
      const bf16x8 a2 = *(const bf16x8*)&c1[rw + cl][kk * 32 + kb * 8];
      const bf16x8 b2v = Wm2tb[(size_t)cl * 32 + kk * 4 + kb];
      acc2 = __builtin_amdgcn_mfma_f32_16x16x32_bf16(a2, b2v, acc2, 0, 0, 0);
    }
    const float bm2v = bm2[cl];
    #pragma unroll
    for (int r = 0; r < 4; ++r) {
      float v = acc2[r] + bm2v;
      float m = v;
      #pragma unroll
      for (int s = 1; s < 16; s <<= 1) m = fmaxf(m, __shfl_xor(m, s));
      const float e = __expf(v - m);
      float ssum = e;
      #pragma unroll
      for (int s = 1; s < 16; s <<= 1) ssum += __shfl_xor(ssum, s);
      const float bb = e / ssum;
      const int grow = m0 + rw + kb * 4 + r;
      Bmat[grow * C + cl] = bb;
      softy[grow * C + cl] = mask[grow] ? labels1h[grow * C + cl] : bb;
    }
  }
}

// ---------------- K3: per-row bitonic sort (determinism) + nbrsum ------------------------------
__global__ __launch_bounds__(256) void sort_nbr(int* __restrict__ rowcnt,
    int* __restrict__ colidx, const float* __restrict__ softy,
    float* __restrict__ nbrsum) {
  __shared__ int cs[4][128];
  const int lane = threadIdx.x & 63, w = threadIdx.x >> 6;
  const int row = blockIdx.x * 4 + w;
  const int cnt = min(rowcnt[row], KMAX);
  if (lane == 0) rowcnt[row] = cnt;
  int e0 = (lane < cnt) ? colidx[row * KMAX + lane] : INF;
  int e1 = (lane + 64 < cnt) ? colidx[row * KMAX + lane + 64] : INF;
  #pragma unroll
  for (int k = 2; k <= 128; k <<= 1) {
    if (k == 128) { const int mn = min(e0, e1), mx = max(e0, e1); e0 = mn; e1 = mx; }
    #pragma unroll
    for (int j = (k == 128) ? 32 : (k >> 1); j > 0; j >>= 1) {
      const bool up = (lane & k) == 0;
      const bool upHi = ((lane + 64) & k) == 0;
      const bool lower = (lane & j) == 0;
      const int o0 = __shfl_xor(e0, j);
      const int o1 = __shfl_xor(e1, j);
      const int mn0 = min(e0, o0), mx0 = max(e0, o0);
      const int mn1 = min(e1, o1), mx1 = max(e1, o1);
      e0 = (up == lower) ? mn0 : mx0;
      e1 = (upHi == lower) ? mn1 : mx1;
    }
  }
  if (lane < cnt) colidx[row * KMAX + lane] = e0;
  if (lane + 64 < cnt) colidx[row * KMAX + lane + 64] = e1;
  cs[w][lane] = e0;
  cs[w][lane + 64] = e1;
  __syncthreads();
  const int c = lane & 15, grp = lane >> 4;
  float acc = 0.f;
  for (int e = grp; e < cnt; e += 4)
    acc += softy[cs[w][e] * C + c];
  acc += __shfl_xor(acc, 16);
  acc += __shfl_xor(acc, 32);
  if (lane < 16) nbrsum[row * C + c] = acc;
}

// ---------------- K4a: partial H[c,c'] and d[c] over row slices --------------------------------
__global__ __launch_bounds__(256) void h_partial(const float* __restrict__ nbrsum,
    const float* __restrict__ softy, float* __restrict__ Hpart) {
  const int t = threadIdx.x;
  const int c = t >> 4, cp = t & 15;
  float acc = 0.f, dacc = 0.f;
  const int j0 = blockIdx.x * (N / 64);
  for (int j = j0; j < j0 + N / 64; ++j) {
    const float nv = nbrsum[j * C + c];
    acc = fmaf(nv, softy[j * C + cp], acc);
    if (cp == 0) dacc += nv;
  }
  Hpart[blockIdx.x * 272 + t] = acc;
  if (cp == 0) Hpart[blockIdx.x * 272 + 256 + c] = dacc;
}

// ---------------- K4b: H = Hun/d ; Q = rownorm((H H^T)*bias) -----------------------------------
__global__ __launch_bounds__(256) void hq_final(const float* __restrict__ Hpart,
    const float* __restrict__ bias, float* __restrict__ H_out,
    float* __restrict__ Q_out, float* __restrict__ Qws) {
  __shared__ float Hs[256], Qs[256], rs[16], dd[16];
  const int t = threadIdx.x;
  const int c = t >> 4, cp = t & 15;
  float acc = 0.f;
  for (int b = 0; b < 64; ++b) acc += Hpart[b * 272 + t];
  if (t < 16) {
    float s = 0.f;
    for (int b = 0; b < 64; ++b) s += Hpart[b * 272 + 256 + t];
    dd[t] = s;
  }
  __syncthreads();
  const float Hv = acc / dd[c];
  Hs[t] = Hv;
  H_out[t] = Hv;
  __syncthreads();
  float q = 0.f;
  for (int k = 0; k < 16; ++k) q = fmaf(Hs[c * 16 + k], Hs[cp * 16 + k], q);
  q *= bias[t];
  Qs[t] = q;
  __syncthreads();
  if (t < 16) {
    float s = 0.f;
    for (int k = 0; k < 16; ++k) s += Qs[t * 16 + k];
    rs[t] = s;
  }
  __syncthreads();
  const float Qv = q / rs[c];
  Q_out[t] = Qv;
  Qws[t] = Qv;
}

// ---------------- K5: fused edge softmax + GCN layer1 + X2 head --------------------------------
__global__ __launch_bounds__(256) void edge_gcn1(const float* __restrict__ Bmat,
    const float* __restrict__ Q, const int* __restrict__ rowcnt,
    const int* __restrict__ colidx, const float* __restrict__ X1,
    const float* __restrict__ b1, const float* __restrict__ W2,
    float* __restrict__ gval, float* __restrict__ X2) {
  __shared__ float Prow[4][16];
  __shared__ float gv[4][128];
  __shared__ int cs[4][128];
  const int lane = threadIdx.x & 63, w = threadIdx.x >> 6;
  const int row = blockIdx.x * 4 + w;
  const int c = lane & 15, grp = lane >> 4;
  float acc = 0.f;
  for (int k = grp * 4; k < grp * 4 + 4; ++k)
    acc = fmaf(Bmat[row * C + k], Q[k * C + c], acc);
  acc += __shfl_xor(acc, 16);
  acc += __shfl_xor(acc, 32);
  if (lane < 16) Prow[w][c] = acc;
  __syncthreads();
  const int cnt = rowcnt[row];
  const int col0 = (lane < cnt) ? colidx[row * KMAX + lane] : 0;
  const int col1 = (lane + 64 < cnt) ? colidx[row * KMAX + lane + 64] : 0;
  float s0 = -1e30f, s1 = -1e30f;
  if (lane < cnt) {
    float s = 0.f;
    for (int k = 0; k < 16; ++k) s = fmaf(Prow[w][k], Bmat[col0 * C + k], s);
    s0 = s;
  }
  if (lane + 64 < cnt) {
    float s = 0.f;
    for (int k = 0; k < 16; ++k) s = fmaf(Prow[w][k], Bmat[col1 * C + k], s);
    s1 = s;
  }
  float m = fmaxf(s0, s1);
  for (int s = 1; s < 64; s <<= 1) m = fmaxf(m, __shfl_xor(m, s));
  const float e0 = __expf(s0 - m), e1 = __expf(s1 - m);
  float ssum = e0 + e1;
  for (int s = 1; s < 64; s <<= 1) ssum += __shfl_xor(ssum, s);
  const float inv = 1.f / ssum;
  const float g0 = e0 * inv, g1 = e1 * inv;
  if (lane < cnt) gval[row * KMAX + lane] = g0;
  if (lane + 64 < cnt) gval[row * KMAX + lane + 64] = g1;
  gv[w][lane] = g0; gv[w][lane + 64] = g1;
  cs[w][lane] = col0; cs[w][lane + 64] = col1;
  __syncthreads();
  float hacc = 0.f;
  for (int e = 0; e < cnt; ++e)
    hacc = fmaf(gv[w][e], X1[(size_t)cs[w][e] * HG + lane], hacc);
  const float h = fmaxf(hacc + b1[lane], 0.f);
  float x[16];
  #pragma unroll
  for (int cc = 0; cc < 16; ++cc) x[cc] = h * W2[lane * C + cc];
  #pragma unroll
  for (int s = 1; s < 64; s <<= 1)
    #pragma unroll
    for (int cc = 0; cc < 16; ++cc) x[cc] += __shfl_xor(x[cc], s);
  float v = x[0];
  #pragma unroll
  for (int cc = 1; cc < 16; ++cc) v = (lane == cc) ? x[cc] : v;
  if (lane < 16) X2[row * C + lane] = v;
}

// ---------------- K6: output = g @ X2 + b2 ; logits = softmax(output) --------------------------
__global__ __launch_bounds__(256) void gcn2(const float* __restrict__ X2,
    const float* __restrict__ b2, const int* __restrict__ rowcnt,
    const int* __restrict__ colidx, const float* __restrict__ gval,
    float* __restrict__ out_logits, float* __restrict__ out_output) {
  const int lane = threadIdx.x & 63;
  const int row = blockIdx.x * 4 + (threadIdx.x >> 6);
  const int c = lane & 15, grp = lane >> 4;
  const int cnt = rowcnt[row];
  float acc = 0.f;
  for (int e = grp; e < cnt; e += 4)
    acc = fmaf(gval[row * KMAX + e], X2[colidx[row * KMAX + e] * C + c], acc);
  acc += __shfl_xor(acc, 16);
  acc += __shfl_xor(acc, 32);
  acc += b2[c];
  float m = acc;
  for (int s = 1; s < 16; s <<= 1) m = fmaxf(m, __shfl_xor(m, s));
  const float e = __expf(acc - m);
  float ssum = e;
  for (int s = 1; s < 16; s <<= 1) ssum += __shfl_xor(ssum, s);
  if (lane < 16) {
    out_output[row * C + c] = acc;
    out_logits[row * C + c] = e / ssum;
  }
}

// ---------------- K7: losses (single block; launch boundary is the fence) ----------------------
__global__ __launch_bounds__(256) void loss_kernel(const float* __restrict__ logits,
    const float* __restrict__ Bmat, const int* __restrict__ idx,
    const int* __restrict__ label, float* __restrict__ out_loss) {
  __shared__ float sg[256], sm[256];
  const int t = threadIdx.x;
  float g = 0.f, m = 0.f;
  for (int i = t; i < 1024; i += 256) {
    const int ii = idx[i], ll = label[i];
    g -= logf(logits[ii * C + ll]);
    m -= logf(Bmat[ii * C + ll]);
  }
  sg[t] = g; sm[t] = m;
  __syncthreads();
  for (int s = 128; s > 0; s >>= 1) {
    if (t < s) { sg[t] += sg[t + s]; sm[t] += sm[t + s]; }
    __syncthreads();
  }
  if (t == 0) out_loss[0] = 1.0f * (sg[0] / 1024.f) + 1.0f * (sm[0] / 1024.f);
}

extern "C" void kernel_launch(void* const* d_in, const int* in_sizes, int n_in,
                              void* d_out, int out_size, void* d_ws, size_t ws_size,
                              hipStream_t stream) {
  const float* feature  = (const float*)d_in[0];
  const float* adj      = (const float*)d_in[1];
  const float* labels1h = (const float*)d_in[2];
  const float* bias     = (const float*)d_in[3];
  const float* Wm1 = (const float*)d_in[4];
  const float* bm1 = (const float*)d_in[5];
  const float* Wm2 = (const float*)d_in[6];
  const float* bm2 = (const float*)d_in[7];
  const float* W1  = (const float*)d_in[8];
  const float* b1  = (const float*)d_in[9];
  const float* W2  = (const float*)d_in[10];
  const float* b2  = (const float*)d_in[11];
  const int* idx   = (const int*)d_in[12];
  const int* label = (const int*)d_in[13];
  const int* mask  = (const int*)d_in[14];

  float* out = (float*)d_out;
  float* logits_o = out;                 // N*C
  float* loss_o   = out + (size_t)N * C; // 1
  float* H_o      = loss_o + 1;          // 256
  float* Q_o      = H_o + 256;           // 256
  float* outp_o   = Q_o + 256;           // N*C

  float* p = (float*)d_ws;
  float* X1     = p; p += (size_t)N * HG;
  float* Bmat   = p; p += (size_t)N * C;
  float* softy  = p; p += (size_t)N * C;
  float* nbrsum = p; p += (size_t)N * C;
  float* X2     = p; p += (size_t)N * C;
  float* Hpart  = p; p += 64 * 272;
  float* Qws    = p; p += 256;
  int* rowcnt = (int*)p; p += N;
  int* colidx = (int*)p; p += (size_t)N * KMAX;
  float* gval = p; p += (size_t)N * KMAX;
  unsigned short* Abf   = (unsigned short*)p;        // N*D bf16
  unsigned short* Wt    = Abf + (size_t)N * D;       // 320*512
  unsigned short* Wm2tb = Wt + 320 * 512;            // 16*256

  prep_kernel<<<(N * D / 8) / 256, 256, 0, stream>>>(feature, Wm1, W1, Wm2, Abf, Wt, Wm2tb, rowcnt);
  adj_tri<<<N / 4, 256, 0, stream>>>(adj, rowcnt, colidx);
  gemm_mlp<<<N / 32, 256, 0, stream>>>((const bf16x8*)Abf, (const bf16x8*)Wt, bm1,
      (const bf16x8*)Wm2tb, bm2, labels1h, mask, Bmat, softy, X1);
  sort_nbr<<<N / 4, 256, 0, stream>>>(rowcnt, colidx, softy, nbrsum);
  h_partial<<<64, 256, 0, stream>>>(nbrsum, softy, Hpart);
  hq_final<<<1, 256, 0, stream>>>(Hpart, bias, H_o, Q_o, Qws);
  edge_gcn1<<<N / 4, 256, 0, stream>>>(Bmat, Qws, rowcnt, colidx, X1, b1, W2, gval, X2);
  gcn2<<<N / 4, 256, 0, stream>>>(X2, b2, rowcnt, colidx, gval, logits_o, outp_o);
  loss_kernel<<<1, 256, 0, stream>>>(logits_o, Bmat, idx, label, loss_o);
}